// Round 7
// baseline (12323.888 us; speedup 1.0000x reference)
//
#include <hip/hip_runtime.h>
#include <hip/hip_bf16.h>

// Problem constants (fixed by the reference)
#define L     4096
#define E     512
#define HID   1024
#define HH    512          // H per direction
#define G4    2048         // 4*H gate rows
#define T_TAG 7
#define START_TAG 4
#define STOP_TAG  5
#define NEGV  (-10000.0f)

#define NBLK  16           // worker blocks per direction (32 units each)
#define SENT  0xFFFFFFFFu  // h sentinel: -NaN, unreachable for real h values

// ---------------------------------------------------------------------------
// Kernel 1: xg[t][j] = emb[sentence[t]] . w_ih[j] + b_ih[j] + b_hh[j]
// for both directions.  Tiled fp32 GEMM, tile 64x64, K-chunks of 32.
// grid (L/64, G4/64, 2), block 256.
// ---------------------------------------------------------------------------
__global__ __launch_bounds__(256)
void xg_kernel(const int* __restrict__ sentence, const float* __restrict__ emb,
               const float* __restrict__ wih_f, const float* __restrict__ bih_f,
               const float* __restrict__ bhh_f,
               const float* __restrict__ wih_b, const float* __restrict__ bih_b,
               const float* __restrict__ bhh_b,
               float* __restrict__ xg_f, float* __restrict__ xg_b)
{
    const int dir = blockIdx.z;
    const float* __restrict__ wih = dir ? wih_b : wih_f;
    const float* __restrict__ bih = dir ? bih_b : bih_f;
    const float* __restrict__ bhh = dir ? bhh_b : bhh_f;
    float* __restrict__ xg = dir ? xg_b : xg_f;

    const int t0 = blockIdx.x * 64;
    const int j0 = blockIdx.y * 64;

    __shared__ float As[32][68];
    __shared__ float Bs[32][68];
    __shared__ int   sent[64];

    const int tid = threadIdx.x;
    if (tid < 64) sent[tid] = sentence[t0 + tid];
    __syncthreads();

    const int tx = tid & 15;
    const int ty = tid >> 4;

    float acc[4][4];
#pragma unroll
    for (int a = 0; a < 4; a++)
#pragma unroll
        for (int b = 0; b < 4; b++) acc[a][b] = 0.f;

    for (int k0 = 0; k0 < E; k0 += 32) {
        __syncthreads();
#pragma unroll
        for (int q = 0; q < 2; q++) {
            const int f  = q * 256 + tid;
            const int i  = f >> 3;
            const int k4 = (f & 7) * 4;
            const float4 av = *(const float4*)(emb + (size_t)sent[i] * E + k0 + k4);
            As[k4 + 0][i] = av.x; As[k4 + 1][i] = av.y;
            As[k4 + 2][i] = av.z; As[k4 + 3][i] = av.w;
            const float4 bv = *(const float4*)(wih + (size_t)(j0 + i) * E + k0 + k4);
            Bs[k4 + 0][i] = bv.x; Bs[k4 + 1][i] = bv.y;
            Bs[k4 + 2][i] = bv.z; Bs[k4 + 3][i] = bv.w;
        }
        __syncthreads();
#pragma unroll
        for (int k = 0; k < 32; k++) {
            const float4 a4 = *(const float4*)&As[k][ty * 4];
            const float4 b4 = *(const float4*)&Bs[k][tx * 4];
            const float a[4] = { a4.x, a4.y, a4.z, a4.w };
            const float b[4] = { b4.x, b4.y, b4.z, b4.w };
#pragma unroll
            for (int ii = 0; ii < 4; ii++)
#pragma unroll
                for (int jj = 0; jj < 4; jj++) acc[ii][jj] += a[ii] * b[jj];
        }
    }

#pragma unroll
    for (int ii = 0; ii < 4; ii++) {
        const int t = t0 + ty * 4 + ii;
#pragma unroll
        for (int jj = 0; jj < 4; jj++) {
            const int j = j0 + tx * 4 + jj;
            xg[(size_t)t * G4 + j] = acc[ii][jj] + bih[j] + bhh[j];
        }
    }
}

// ---------------------------------------------------------------------------
// Kernel 2: bidirectional LSTM recurrence.  Cooperative, 32 blocks x 512.
// Blocks 0..15 = forward, 16..31 = backward.  Each block owns 32 hidden
// units; each WAVE owns 4 complete units (16 gate rows) -> gate math is
// wave-local: no glds, ONE barrier per step.
//   * columns: lane handles cols {lane, lane+64, ..., lane+448} -> h_lds
//     reads are 8x ds_read_b32 stride-64 = conflict-free (2 lanes/bank).
//   * butterfly leaves lane l holding register index bitrev4(l); we load
//     w_reg[rr] with weight row bitrev4(rr) so the reversal CANCELS:
//     after reduction lane l holds weight row l = (unit<<2)|gate.
// Sync: relaxed agent-scope atomics + NaN sentinel (proven R2/R5 mechanism),
// one word per thread, ping-pong LDS staging.
// ---------------------------------------------------------------------------
__global__ __launch_bounds__(512)
void lstm_kernel(const float* __restrict__ xg_f, const float* __restrict__ xg_b,
                 const float* __restrict__ whh_f, const float* __restrict__ whh_b,
                 float* __restrict__ hf, float* __restrict__ hb)
{
    const int dir = blockIdx.x >> 4;           // 0 fwd, 1 bwd
    const int rnk = blockIdx.x & 15;           // 0..15

    const float* __restrict__ xg  = dir ? xg_b  : xg_f;
    const float* __restrict__ whh = dir ? whh_b : whh_f;
    float* __restrict__ hout = dir ? hb : hf;

    const int tid  = threadIdx.x;
    const int wave = tid >> 6;        // 0..7, owns units u0+wave*4 .. +3
    const int lane = tid & 63;
    const int u0   = rnk * 32;

    // w_reg[rr] holds weight row bitrev4(rr):  rbit = bitrev4(rr),
    // gt = rbit&3, un = rbit>>2, row = gt*HH + u0 + wave*4 + un.
    // Per-(rr,k) global load is 64 consecutive words (coalesced).
    float w_reg[16][8];
#pragma unroll
    for (int rr = 0; rr < 16; rr++) {
        const int rbit = ((rr & 1) << 3) | ((rr & 2) << 1) |
                         ((rr & 4) >> 1) | ((rr & 8) >> 3);   // bitrev4
        const int gt = rbit & 3, un = rbit >> 2;
        const size_t row = (size_t)(gt * HH + u0 + (wave << 2) + un);
#pragma unroll
        for (int k = 0; k < 8; k++)
            w_reg[rr][k] = whh[row * HH + (size_t)(k * 64 + lane)];
    }

    __shared__ float h_lds[2][HH];    // ping-pong h[t-1] staging
    float c_state = 0.f;              // live only for lane < 4
    const int uu = u0 + (wave << 2) + lane;   // unit id (valid for lane < 4)

    // xg prefetch registers (gate lanes only: lane < 4)
    float xqi = 0.f, xqf = 0.f, xqg = 0.f, xqo = 0.f;
    if (lane < 4) {
        const float* xgt = xg + (size_t)(dir ? (L - 1) : 0) * G4;
        xqi = xgt[uu];            xqf = xgt[HH + uu];
        xqg = xgt[2 * HH + uu];   xqo = xgt[3 * HH + uu];
    }

    for (int s = 0; s < L; s++) {
        const int t = dir ? (L - 1 - s) : s;
        const int p = s & 1;

        // poll my single word of h[t-1], deposit into LDS
        unsigned int v = 0;           // s==0: h = 0
        if (s > 0) {
            const int tp = dir ? (t + 1) : (t - 1);
            const unsigned int* hp =
                (const unsigned int*)(hout + (size_t)tp * HH) + tid;
            do {
                v = __hip_atomic_load(hp, __ATOMIC_RELAXED,
                                      __HIP_MEMORY_SCOPE_AGENT);
            } while (v == SENT);
        }
        h_lds[p][tid] = __uint_as_float(v);
        __syncthreads();                               // the only barrier

        // matvec: 16 rows x my 8 strided cols (conflict-free b32 reads)
        float hv[8];
#pragma unroll
        for (int k = 0; k < 8; k++) hv[k] = h_lds[p][k * 64 + lane];

        float acc[16];
#pragma unroll
        for (int rr = 0; rr < 16; rr++) {
            float a = 0.f;
#pragma unroll
            for (int k = 0; k < 8; k++) a += w_reg[rr][k] * hv[k];
            acc[rr] = a;
        }

        // register-compacting butterfly across 64 lanes (17 shuffles).
        // After stage x: lane bit(log2 x) selects register-half; final:
        // lane l holds full sum of register index bitrev4(l&15) = row l.
        {
            const bool b0 = lane & 1;
#pragma unroll
            for (int r = 0; r < 8; r++) {
                const float send = b0 ? acc[r] : acc[r + 8];
                const float recv = __shfl_xor(send, 1, 64);
                acc[r] = (b0 ? acc[r + 8] : acc[r]) + recv;
            }
            const bool b1 = lane & 2;
#pragma unroll
            for (int r = 0; r < 4; r++) {
                const float send = b1 ? acc[r] : acc[r + 4];
                const float recv = __shfl_xor(send, 2, 64);
                acc[r] = (b1 ? acc[r + 4] : acc[r]) + recv;
            }
            const bool b2 = lane & 4;
#pragma unroll
            for (int r = 0; r < 2; r++) {
                const float send = b2 ? acc[r] : acc[r + 2];
                const float recv = __shfl_xor(send, 4, 64);
                acc[r] = (b2 ? acc[r + 2] : acc[r]) + recv;
            }
            const bool b3 = lane & 8;
            {
                const float send = b3 ? acc[0] : acc[1];
                const float recv = __shfl_xor(send, 8, 64);
                acc[0] = (b3 ? acc[1] : acc[0]) + recv;
            }
            acc[0] += __shfl_xor(acc[0], 16, 64);
            acc[0] += __shfl_xor(acc[0], 32, 64);
        }
        // lane l holds S(row l), row l = (unit<<2) | gate  (l < 16)
        const float S = acc[0];
        const int base = (lane & 3) << 2;          // unit u = lane (lane<4)
        const float sv_i = __shfl(S, base + 0, 64);
        const float sv_f = __shfl(S, base + 1, 64);
        const float sv_g = __shfl(S, base + 2, 64);
        const float sv_o = __shfl(S, base + 3, 64);

        if (lane < 4) {
            float iv = sv_i + xqi;
            float fv = sv_f + xqf;
            float gv = sv_g + xqg;
            float ov = sv_o + xqo;
            iv = 1.f / (1.f + expf(-iv));
            fv = 1.f / (1.f + expf(-fv));
            gv = tanhf(gv);
            ov = 1.f / (1.f + expf(-ov));
            c_state = fv * c_state + iv * gv;
            const float hval = ov * tanhf(c_state);
            __hip_atomic_store((unsigned int*)&hout[(size_t)t * HH + uu],
                               __float_as_uint(hval), __ATOMIC_RELAXED,
                               __HIP_MEMORY_SCOPE_AGENT);
            // prefetch next step's xg (hides under next poll + matvec)
            if (s + 1 < L) {
                const int tn = dir ? (t - 1) : (t + 1);
                const float* xgt = xg + (size_t)tn * G4;
                xqi = xgt[uu];            xqf = xgt[HH + uu];
                xqg = xgt[2 * HH + uu];   xqo = xgt[3 * HH + uu];
            }
        }
        // no trailing barrier: next iteration writes h_lds[p^1] (ping-pong);
        // the next barrier orders everything before any read of it.
    }
}

// ---------------------------------------------------------------------------
// Kernel 3: feats[t][i] = [hf[t],hb[t]] . w_out[i] + b_out[i]
// grid L blocks, block 256.  feats stored with stride 8.
// ---------------------------------------------------------------------------
__global__ __launch_bounds__(256)
void feats_kernel(const float* __restrict__ hf, const float* __restrict__ hb,
                  const float* __restrict__ wout, const float* __restrict__ bout,
                  float* __restrict__ feats)
{
    const int t   = blockIdx.x;
    const int tid = threadIdx.x;

    float acc[T_TAG];
#pragma unroll
    for (int i = 0; i < T_TAG; i++) acc[i] = 0.f;

    for (int c = tid; c < HID; c += 256) {
        const float v = (c < HH) ? hf[(size_t)t * HH + c]
                                 : hb[(size_t)t * HH + (c - HH)];
#pragma unroll
        for (int i = 0; i < T_TAG; i++) acc[i] += v * wout[i * HID + c];
    }
#pragma unroll
    for (int m = 1; m < 64; m <<= 1) {
#pragma unroll
        for (int i = 0; i < T_TAG; i++) acc[i] += __shfl_xor(acc[i], m, 64);
    }

    __shared__ float red[4][T_TAG];
    const int wave = tid >> 6, lane = tid & 63;
    if (lane == 0) {
#pragma unroll
        for (int i = 0; i < T_TAG; i++) red[wave][i] = acc[i];
    }
    __syncthreads();
    if (tid < T_TAG) {
        feats[(size_t)t * 8 + tid] =
            red[0][tid] + red[1][tid] + red[2][tid] + red[3][tid] + bout[tid];
    }
}

// ---------------------------------------------------------------------------
// Kernel 4: Viterbi forward + backtrace.  One wave.
// ---------------------------------------------------------------------------
__global__ __launch_bounds__(64)
void viterbi_kernel(const float* __restrict__ feats, const float* __restrict__ trans,
                    float* __restrict__ out)
{
    __shared__ unsigned char bp[L][T_TAG];

    const int tid = threadIdx.x;     // 0..63
    const int i = tid >> 3, j = tid & 7;
    const bool valid = (i < T_TAG) && (j < T_TAG);
    const float trij = valid ? trans[i * T_TAG + j] : -1e30f;

    float fv;
    if (j < T_TAG) fv = (j == START_TAG) ? 0.f : NEGV;
    else           fv = -1e30f;

    const int ieff = (i < T_TAG) ? i : 0;
    float fq[8];
#pragma unroll
    for (int p = 0; p < 8; p++) fq[p] = feats[(size_t)p * 8 + ieff];

    for (int t = 0; t < L; t++) {
        const float sc = fv + trij;
        float best = sc; int bj = j;
#pragma unroll
        for (int m = 1; m < 8; m <<= 1) {
            const float ov = __shfl_xor(best, m, 8);
            const int   oj = __shfl_xor(bj, m, 8);
            if (ov > best || (ov == best && oj < bj)) { best = ov; bj = oj; }
        }
        const float f_t = fq[t & 7];
        if (t + 8 < L) fq[t & 7] = feats[(size_t)(t + 8) * 8 + ieff];
        const float fvnew = best + f_t;          // for dest tag == i
        if (valid && j == 0) bp[t][i] = (unsigned char)bj;
        const float nf = __shfl(fvnew, (j < T_TAG) ? j * 8 : 0, 64);
        fv = (j < T_TAG) ? nf : -1e30f;
    }

    float term = fv + ((j < T_TAG) ? trans[STOP_TAG * T_TAG + j] : -1e30f);
    float bestt = term; int bt = j;
#pragma unroll
    for (int m = 1; m < 8; m <<= 1) {
        const float ov = __shfl_xor(bestt, m, 8);
        const int   oj = __shfl_xor(bt, m, 8);
        if (ov > bestt || (ov == bestt && oj < bt)) { bestt = ov; bt = oj; }
    }

    if (tid == 0) {
        out[L] = bestt;
        int tag = bt;
        out[L - 1] = (float)tag;
        for (int t = L - 1; t >= 1; t--) {
            tag = bp[t][tag];
            out[t - 1] = (float)tag;
        }
    }
}

// ---------------------------------------------------------------------------
extern "C" void kernel_launch(void* const* d_in, const int* in_sizes, int n_in,
                              void* d_out, int out_size, void* d_ws, size_t ws_size,
                              hipStream_t stream)
{
    const int*   sentence = (const int*)  d_in[0];
    const float* emb      = (const float*)d_in[1];
    const float* wih_f    = (const float*)d_in[2];
    const float* whh_f    = (const float*)d_in[3];
    const float* bih_f    = (const float*)d_in[4];
    const float* bhh_f    = (const float*)d_in[5];
    const float* wih_b    = (const float*)d_in[6];
    const float* whh_b    = (const float*)d_in[7];
    const float* bih_b    = (const float*)d_in[8];
    const float* bhh_b    = (const float*)d_in[9];
    const float* wout     = (const float*)d_in[10];
    const float* bout     = (const float*)d_in[11];
    const float* trans    = (const float*)d_in[12];
    float* out = (float*)d_out;

    char* ws = (char*)d_ws;
    float* xg_f   = (float*)(ws + 1024);
    float* xg_b   = xg_f  + (size_t)L * G4;
    float* hfbuf  = xg_b  + (size_t)L * G4;
    float* hbbuf  = hfbuf + (size_t)L * HH;
    float* featsb = hbbuf + (size_t)L * HH;
    // total: 1024 + 2*L*G4*4 + 2*L*HH*4 + L*8*4  ~= 84 MB

    // h buffers -> sentinel (0xFF bytes = -NaN); data-arrival sync relies on it
    hipMemsetAsync(hfbuf, 0xFF, (size_t)2 * L * HH * sizeof(float), stream);

    hipLaunchKernelGGL(xg_kernel, dim3(L / 64, G4 / 64, 2), dim3(256), 0, stream,
                       sentence, emb, wih_f, bih_f, bhh_f, wih_b, bih_b, bhh_b,
                       xg_f, xg_b);

    void* args[] = { (void*)&xg_f, (void*)&xg_b, (void*)&whh_f, (void*)&whh_b,
                     (void*)&hfbuf, (void*)&hbbuf };
    hipLaunchCooperativeKernel((void*)lstm_kernel, dim3(2 * NBLK), dim3(512),
                               args, 0, stream);

    hipLaunchKernelGGL(feats_kernel, dim3(L), dim3(256), 0, stream,
                       hfbuf, hbbuf, wout, bout, featsb);

    hipLaunchKernelGGL(viterbi_kernel, dim3(1), dim3(64), 0, stream,
                       featsb, trans, out);
}

// Round 8
// 9919.065 us; speedup vs baseline: 1.2424x; 1.2424x over previous
//
#include <hip/hip_runtime.h>
#include <hip/hip_bf16.h>

// Problem constants (fixed by the reference)
#define L     4096
#define E     512
#define HID   1024
#define HH    512          // H per direction
#define G4    2048         // 4*H gate rows
#define T_TAG 7
#define START_TAG 4
#define STOP_TAG  5
#define NEGV  (-10000.0f)

#define NBLK  16           // worker blocks per direction (32 units each)
#define SENT  0xFFFFFFFFu  // h sentinel: -NaN, unreachable for real h values

// ---------------------------------------------------------------------------
// Kernel 1: xg[t][j] = emb[sentence[t]] . w_ih[j] + b_ih[j] + b_hh[j]
// for both directions.  Tiled fp32 GEMM, tile 64x64, K-chunks of 32.
// grid (L/64, G4/64, 2), block 256.
// ---------------------------------------------------------------------------
__global__ __launch_bounds__(256)
void xg_kernel(const int* __restrict__ sentence, const float* __restrict__ emb,
               const float* __restrict__ wih_f, const float* __restrict__ bih_f,
               const float* __restrict__ bhh_f,
               const float* __restrict__ wih_b, const float* __restrict__ bih_b,
               const float* __restrict__ bhh_b,
               float* __restrict__ xg_f, float* __restrict__ xg_b)
{
    const int dir = blockIdx.z;
    const float* __restrict__ wih = dir ? wih_b : wih_f;
    const float* __restrict__ bih = dir ? bih_b : bih_f;
    const float* __restrict__ bhh = dir ? bhh_b : bhh_f;
    float* __restrict__ xg = dir ? xg_b : xg_f;

    const int t0 = blockIdx.x * 64;
    const int j0 = blockIdx.y * 64;

    __shared__ float As[32][68];
    __shared__ float Bs[32][68];
    __shared__ int   sent[64];

    const int tid = threadIdx.x;
    if (tid < 64) sent[tid] = sentence[t0 + tid];
    __syncthreads();

    const int tx = tid & 15;
    const int ty = tid >> 4;

    float acc[4][4];
#pragma unroll
    for (int a = 0; a < 4; a++)
#pragma unroll
        for (int b = 0; b < 4; b++) acc[a][b] = 0.f;

    for (int k0 = 0; k0 < E; k0 += 32) {
        __syncthreads();
#pragma unroll
        for (int q = 0; q < 2; q++) {
            const int f  = q * 256 + tid;
            const int i  = f >> 3;
            const int k4 = (f & 7) * 4;
            const float4 av = *(const float4*)(emb + (size_t)sent[i] * E + k0 + k4);
            As[k4 + 0][i] = av.x; As[k4 + 1][i] = av.y;
            As[k4 + 2][i] = av.z; As[k4 + 3][i] = av.w;
            const float4 bv = *(const float4*)(wih + (size_t)(j0 + i) * E + k0 + k4);
            Bs[k4 + 0][i] = bv.x; Bs[k4 + 1][i] = bv.y;
            Bs[k4 + 2][i] = bv.z; Bs[k4 + 3][i] = bv.w;
        }
        __syncthreads();
#pragma unroll
        for (int k = 0; k < 32; k++) {
            const float4 a4 = *(const float4*)&As[k][ty * 4];
            const float4 b4 = *(const float4*)&Bs[k][tx * 4];
            const float a[4] = { a4.x, a4.y, a4.z, a4.w };
            const float b[4] = { b4.x, b4.y, b4.z, b4.w };
#pragma unroll
            for (int ii = 0; ii < 4; ii++)
#pragma unroll
                for (int jj = 0; jj < 4; jj++) acc[ii][jj] += a[ii] * b[jj];
        }
    }

#pragma unroll
    for (int ii = 0; ii < 4; ii++) {
        const int t = t0 + ty * 4 + ii;
#pragma unroll
        for (int jj = 0; jj < 4; jj++) {
            const int j = j0 + tx * 4 + jj;
            xg[(size_t)t * G4 + j] = acc[ii][jj] + bih[j] + bhh[j];
        }
    }
}

// ---------------------------------------------------------------------------
// Kernel 2: bidirectional LSTM recurrence.  Cooperative, 32 blocks x 512.
// Blocks 0..15 = forward, 16..31 = backward.  Each block owns 32 hidden
// units (128 gate rows); W_hh slice in registers (w[16][8], 128 VGPR/lane).
// Structure = R5 (proven fastest): wave (gate g, half jh) owns 16 rows of
// one gate; glds handoff; gate math + h store + xg prefetch centralized in
// tid<32 -> all global transactions are 128B coalesced.
// LDS pattern = R7 (proven conflict-free): lane handles columns
// {lane, lane+64, ..., lane+448} -> h_lds reads are 8x ds_read_b32
// stride-64 (2 lanes/bank = free); weights loaded k*64+lane (coalesced).
// Sync: relaxed agent-scope atomics + NaN sentinel, one poll word/thread,
// ping-pong LDS staging, 2 barriers/step.
// ---------------------------------------------------------------------------
__global__ __launch_bounds__(512)
void lstm_kernel(const float* __restrict__ xg_f, const float* __restrict__ xg_b,
                 const float* __restrict__ whh_f, const float* __restrict__ whh_b,
                 float* __restrict__ hf, float* __restrict__ hb)
{
    const int dir = blockIdx.x >> 4;           // 0 fwd, 1 bwd
    const int rnk = blockIdx.x & 15;           // 0..15

    const float* __restrict__ xg  = dir ? xg_b  : xg_f;
    const float* __restrict__ whh = dir ? whh_b : whh_f;
    float* __restrict__ hout = dir ? hb : hf;

    const int tid  = threadIdx.x;
    const int wave = tid >> 6;        // 0..7
    const int lane = tid & 63;
    const int g    = wave >> 1;       // gate: 0=i 1=f 2=g 3=o
    const int jh   = wave & 1;        // unit half (0: 0..15, 1: 16..31)
    const int u0   = rnk * 32;

    // weights: w[rr][k] = whh[(g*HH + u0 + jh*16 + rr)*HH + k*64 + lane]
    // (transposed columns; per-(rr,k) load is 64 consecutive words)
    float w[16][8];
#pragma unroll
    for (int rr = 0; rr < 16; rr++) {
        const size_t row = (size_t)(g * HH + u0 + jh * 16 + rr);
#pragma unroll
        for (int k = 0; k < 8; k++)
            w[rr][k] = whh[row * HH + (size_t)(k * 64 + lane)];
    }

    __shared__ float h_lds[2][HH];    // ping-pong h[t-1] staging
    __shared__ float glds[8][16];     // per-wave row sums
    float c_state = 0.f;              // live only for tid < 32
    const int uu = u0 + (tid & 31);

    // xg prefetch registers (gate threads only, tid < 32: coalesced 128B)
    float xq0 = 0.f, xq1 = 0.f, xq2 = 0.f, xq3 = 0.f;
    if (tid < 32) {
        const float* xgt = xg + (size_t)(dir ? (L - 1) : 0) * G4;
        xq0 = xgt[uu];            xq1 = xgt[HH + uu];
        xq2 = xgt[2 * HH + uu];   xq3 = xgt[3 * HH + uu];
    }

    for (int s = 0; s < L; s++) {
        const int t = dir ? (L - 1 - s) : s;
        const int p = s & 1;

        // A/B: poll my single word of h[t-1], deposit into LDS
        unsigned int v = 0;           // s==0: h = 0
        if (s > 0) {
            const int tp = dir ? (t + 1) : (t - 1);
            const unsigned int* hp =
                (const unsigned int*)(hout + (size_t)tp * HH) + tid;
            do {
                v = __hip_atomic_load(hp, __ATOMIC_RELAXED,
                                      __HIP_MEMORY_SCOPE_AGENT);
            } while (v == SENT);
        }
        h_lds[p][tid] = __uint_as_float(v);
        __syncthreads();                               // barrier 1

        // D: matvec on my 8 strided cols for my wave's 16 rows
        float hv[8];
#pragma unroll
        for (int k = 0; k < 8; k++) hv[k] = h_lds[p][k * 64 + lane];

        float acc[16];
#pragma unroll
        for (int rr = 0; rr < 16; rr++) {
            float a = 0.f;
#pragma unroll
            for (int k = 0; k < 8; k++) a += w[rr][k] * hv[k];
            acc[rr] = a;
        }

        // register-compacting butterfly reduction across 64 lanes
        {
            const bool b0 = lane & 1;
#pragma unroll
            for (int r = 0; r < 8; r++) {
                const float send = b0 ? acc[r] : acc[r + 8];
                const float recv = __shfl_xor(send, 1, 64);
                acc[r] = (b0 ? acc[r + 8] : acc[r]) + recv;
            }
            const bool b1 = lane & 2;
#pragma unroll
            for (int r = 0; r < 4; r++) {
                const float send = b1 ? acc[r] : acc[r + 4];
                const float recv = __shfl_xor(send, 2, 64);
                acc[r] = (b1 ? acc[r + 4] : acc[r]) + recv;
            }
            const bool b2 = lane & 4;
#pragma unroll
            for (int r = 0; r < 2; r++) {
                const float send = b2 ? acc[r] : acc[r + 2];
                const float recv = __shfl_xor(send, 4, 64);
                acc[r] = (b2 ? acc[r + 2] : acc[r]) + recv;
            }
            const bool b3 = lane & 8;
            {
                const float send = b3 ? acc[0] : acc[1];
                const float recv = __shfl_xor(send, 8, 64);
                acc[0] = (b3 ? acc[1] : acc[0]) + recv;
            }
            acc[0] += __shfl_xor(acc[0], 16, 64);
            acc[0] += __shfl_xor(acc[0], 32, 64);
        }
        // lane l (<16) holds local row R = bitrev4(l)
        if (lane < 16) {
            const int R = ((lane & 1) << 3) | ((lane & 2) << 1) |
                          ((lane & 4) >> 1) | ((lane & 8) >> 3);
            glds[wave][R] = acc[0];
        }
        __syncthreads();                               // barrier 2

        // F: gate math + coalesced h store (32 gate threads = wave 0)
        if (tid < 32) {
            const int j   = tid;         // unit within block
            const int jh_ = j >> 4;      // half
            const int rr  = j & 15;
            float iv = glds[0 + jh_][rr] + xq0;
            float fv = glds[2 + jh_][rr] + xq1;
            float gv = glds[4 + jh_][rr] + xq2;
            float ov = glds[6 + jh_][rr] + xq3;
            iv = 1.f / (1.f + expf(-iv));
            fv = 1.f / (1.f + expf(-fv));
            gv = tanhf(gv);
            ov = 1.f / (1.f + expf(-ov));
            c_state = fv * c_state + iv * gv;
            const float hval = ov * tanhf(c_state);
            __hip_atomic_store((unsigned int*)&hout[(size_t)t * HH + uu],
                               __float_as_uint(hval), __ATOMIC_RELAXED,
                               __HIP_MEMORY_SCOPE_AGENT);
            // prefetch next step's xg (hides under next poll + matvec)
            if (s + 1 < L) {
                const int tn = dir ? (t - 1) : (t + 1);
                const float* xgt = xg + (size_t)tn * G4;
                xq0 = xgt[uu];            xq1 = xgt[HH + uu];
                xq2 = xgt[2 * HH + uu];   xq3 = xgt[3 * HH + uu];
            }
        }
        // no trailing barrier: next iteration writes h_lds[p^1] (ping-pong),
        // and glds is only rewritten after the next barrier 1.
    }
}

// ---------------------------------------------------------------------------
// Kernel 3: feats[t][i] = [hf[t],hb[t]] . w_out[i] + b_out[i]
// grid L blocks, block 256.  feats stored with stride 8.
// ---------------------------------------------------------------------------
__global__ __launch_bounds__(256)
void feats_kernel(const float* __restrict__ hf, const float* __restrict__ hb,
                  const float* __restrict__ wout, const float* __restrict__ bout,
                  float* __restrict__ feats)
{
    const int t   = blockIdx.x;
    const int tid = threadIdx.x;

    float acc[T_TAG];
#pragma unroll
    for (int i = 0; i < T_TAG; i++) acc[i] = 0.f;

    for (int c = tid; c < HID; c += 256) {
        const float v = (c < HH) ? hf[(size_t)t * HH + c]
                                 : hb[(size_t)t * HH + (c - HH)];
#pragma unroll
        for (int i = 0; i < T_TAG; i++) acc[i] += v * wout[i * HID + c];
    }
#pragma unroll
    for (int m = 1; m < 64; m <<= 1) {
#pragma unroll
        for (int i = 0; i < T_TAG; i++) acc[i] += __shfl_xor(acc[i], m, 64);
    }

    __shared__ float red[4][T_TAG];
    const int wave = tid >> 6, lane = tid & 63;
    if (lane == 0) {
#pragma unroll
        for (int i = 0; i < T_TAG; i++) red[wave][i] = acc[i];
    }
    __syncthreads();
    if (tid < T_TAG) {
        feats[(size_t)t * 8 + tid] =
            red[0][tid] + red[1][tid] + red[2][tid] + red[3][tid] + bout[tid];
    }
}

// ---------------------------------------------------------------------------
// Kernel 4: Viterbi forward + backtrace.  One wave.
// ---------------------------------------------------------------------------
__global__ __launch_bounds__(64)
void viterbi_kernel(const float* __restrict__ feats, const float* __restrict__ trans,
                    float* __restrict__ out)
{
    __shared__ unsigned char bp[L][T_TAG];

    const int tid = threadIdx.x;     // 0..63
    const int i = tid >> 3, j = tid & 7;
    const bool valid = (i < T_TAG) && (j < T_TAG);
    const float trij = valid ? trans[i * T_TAG + j] : -1e30f;

    float fv;
    if (j < T_TAG) fv = (j == START_TAG) ? 0.f : NEGV;
    else           fv = -1e30f;

    const int ieff = (i < T_TAG) ? i : 0;
    float fq[8];
#pragma unroll
    for (int p = 0; p < 8; p++) fq[p] = feats[(size_t)p * 8 + ieff];

    for (int t = 0; t < L; t++) {
        const float sc = fv + trij;
        float best = sc; int bj = j;
#pragma unroll
        for (int m = 1; m < 8; m <<= 1) {
            const float ov = __shfl_xor(best, m, 8);
            const int   oj = __shfl_xor(bj, m, 8);
            if (ov > best || (ov == best && oj < bj)) { best = ov; bj = oj; }
        }
        const float f_t = fq[t & 7];
        if (t + 8 < L) fq[t & 7] = feats[(size_t)(t + 8) * 8 + ieff];
        const float fvnew = best + f_t;          // for dest tag == i
        if (valid && j == 0) bp[t][i] = (unsigned char)bj;
        const float nf = __shfl(fvnew, (j < T_TAG) ? j * 8 : 0, 64);
        fv = (j < T_TAG) ? nf : -1e30f;
    }

    float term = fv + ((j < T_TAG) ? trans[STOP_TAG * T_TAG + j] : -1e30f);
    float bestt = term; int bt = j;
#pragma unroll
    for (int m = 1; m < 8; m <<= 1) {
        const float ov = __shfl_xor(bestt, m, 8);
        const int   oj = __shfl_xor(bt, m, 8);
        if (ov > bestt || (ov == bestt && oj < bt)) { bestt = ov; bt = oj; }
    }

    if (tid == 0) {
        out[L] = bestt;
        int tag = bt;
        out[L - 1] = (float)tag;
        for (int t = L - 1; t >= 1; t--) {
            tag = bp[t][tag];
            out[t - 1] = (float)tag;
        }
    }
}

// ---------------------------------------------------------------------------
extern "C" void kernel_launch(void* const* d_in, const int* in_sizes, int n_in,
                              void* d_out, int out_size, void* d_ws, size_t ws_size,
                              hipStream_t stream)
{
    const int*   sentence = (const int*)  d_in[0];
    const float* emb      = (const float*)d_in[1];
    const float* wih_f    = (const float*)d_in[2];
    const float* whh_f    = (const float*)d_in[3];
    const float* bih_f    = (const float*)d_in[4];
    const float* bhh_f    = (const float*)d_in[5];
    const float* wih_b    = (const float*)d_in[6];
    const float* whh_b    = (const float*)d_in[7];
    const float* bih_b    = (const float*)d_in[8];
    const float* bhh_b    = (const float*)d_in[9];
    const float* wout     = (const float*)d_in[10];
    const float* bout     = (const float*)d_in[11];
    const float* trans    = (const float*)d_in[12];
    float* out = (float*)d_out;

    char* ws = (char*)d_ws;
    float* xg_f   = (float*)(ws + 1024);
    float* xg_b   = xg_f  + (size_t)L * G4;
    float* hfbuf  = xg_b  + (size_t)L * G4;
    float* hbbuf  = hfbuf + (size_t)L * HH;
    float* featsb = hbbuf + (size_t)L * HH;
    // total: 1024 + 2*L*G4*4 + 2*L*HH*4 + L*8*4  ~= 84 MB

    // h buffers -> sentinel (0xFF bytes = -NaN); data-arrival sync relies on it
    hipMemsetAsync(hfbuf, 0xFF, (size_t)2 * L * HH * sizeof(float), stream);

    hipLaunchKernelGGL(xg_kernel, dim3(L / 64, G4 / 64, 2), dim3(256), 0, stream,
                       sentence, emb, wih_f, bih_f, bhh_f, wih_b, bih_b, bhh_b,
                       xg_f, xg_b);

    void* args[] = { (void*)&xg_f, (void*)&xg_b, (void*)&whh_f, (void*)&whh_b,
                     (void*)&hfbuf, (void*)&hbbuf };
    hipLaunchCooperativeKernel((void*)lstm_kernel, dim3(2 * NBLK), dim3(512),
                               args, 0, stream);

    hipLaunchKernelGGL(feats_kernel, dim3(L), dim3(256), 0, stream,
                       hfbuf, hbbuf, wout, bout, featsb);

    hipLaunchKernelGGL(viterbi_kernel, dim3(1), dim3(64), 0, stream,
                       featsb, trans, out);
}

// Round 9
// 9808.099 us; speedup vs baseline: 1.2565x; 1.0113x over previous
//
#include <hip/hip_runtime.h>
#include <hip/hip_bf16.h>

// Problem constants (fixed by the reference)
#define L     4096
#define E     512
#define HID   1024
#define HH    512          // H per direction
#define G4    2048         // 4*H gate rows
#define T_TAG 7
#define START_TAG 4
#define STOP_TAG  5
#define NEGV  (-10000.0f)

#define NWRK  32           // worker blocks (16 per direction)
#define NHELP 224          // helper blocks (xg tiles, then feats rows)
#define NTILE (64 * 2 * 32)  // (L/64 s-chunks) x 2 dirs x (G4/64 j-tiles)
#define SENT  0xFFFFFFFFu  // h sentinel: -NaN, unreachable for real h values

__device__ __forceinline__ float aload_f(const float* p) {
    const unsigned int v = __hip_atomic_load((const unsigned int*)p,
                                             __ATOMIC_RELAXED,
                                             __HIP_MEMORY_SCOPE_AGENT);
    return __uint_as_float(v);
}
__device__ __forceinline__ void astore_f(float* p, float x) {
    __hip_atomic_store((unsigned int*)p, __float_as_uint(x),
                       __ATOMIC_RELAXED, __HIP_MEMORY_SCOPE_AGENT);
}

// ---------------------------------------------------------------------------
// Fused cooperative kernel, 256 blocks x 512.
//  blocks 0..31   : bidirectional LSTM recurrence (R8 structure, unchanged
//                   floor: store->IF->poll chain ~1.9us/step)
//  blocks 32..255 : helpers. Phase 1: xg = x@W_ih^T + biases, 64x64 tiles in
//                   timestep order for both dirs; per-(dir,chunk) readiness
//                   counters (release agent atomics; xg stored write-through).
//                   Phase 2: feats rows, polling h sentinels directly.
// ---------------------------------------------------------------------------
__global__ __launch_bounds__(512)
void fused_kernel(const int* __restrict__ sentence, const float* __restrict__ emb,
                  const float* __restrict__ wih_f, const float* __restrict__ bih_f,
                  const float* __restrict__ bhh_f,
                  const float* __restrict__ wih_b, const float* __restrict__ bih_b,
                  const float* __restrict__ bhh_b,
                  const float* __restrict__ whh_f, const float* __restrict__ whh_b,
                  const float* __restrict__ wout, const float* __restrict__ bout,
                  float* __restrict__ xg_f, float* __restrict__ xg_b,
                  float* __restrict__ hf, float* __restrict__ hb,
                  float* __restrict__ feats, int* cnt)
{
    const int bid = blockIdx.x;
    const int tid = threadIdx.x;

    // ---- LDS (sum of both roles; 1 block/CU, fits easily) ----
    __shared__ float h_lds[2][HH];    // worker: ping-pong h staging
    __shared__ float glds[8][16];     // worker: per-wave row sums
    __shared__ float As[32][68];      // helper: x tile
    __shared__ float Bs[32][68];      // helper: w_ih tile
    __shared__ int   sent_s[64];      // helper: sentence ids
    __shared__ float red_s[8][8];     // helper: feats reduction

    if (bid < NWRK) {
        // =================== WORKER: LSTM recurrence ===================
        const int dir = bid >> 4;            // 0 fwd, 1 bwd
        const int rnk = bid & 15;            // 0..15

        const float* __restrict__ xg  = dir ? xg_b  : xg_f;
        const float* __restrict__ whh = dir ? whh_b : whh_f;
        float* __restrict__ hout = dir ? hb : hf;

        const int wave = tid >> 6;
        const int lane = tid & 63;
        const int g    = wave >> 1;          // gate: 0=i 1=f 2=g 3=o
        const int jh   = wave & 1;           // unit half
        const int u0   = rnk * 32;

        // weights: w[rr][k] = whh[(g*HH + u0 + jh*16 + rr)*HH + k*64 + lane]
        float w[16][8];
#pragma unroll
        for (int rr = 0; rr < 16; rr++) {
            const size_t row = (size_t)(g * HH + u0 + jh * 16 + rr);
#pragma unroll
            for (int k = 0; k < 8; k++)
                w[rr][k] = whh[row * HH + (size_t)(k * 64 + lane)];
        }

        float c_state = 0.f;                 // live only for tid < 32
        const int uu = u0 + (tid & 31);

        auto wait_chunk = [&](int tc) {
            const int* cp = cnt + dir * 64 + tc;
            while (__hip_atomic_load(cp, __ATOMIC_ACQUIRE,
                                     __HIP_MEMORY_SCOPE_AGENT) < 32) {
                __builtin_amdgcn_s_sleep(1);
            }
        };

        // xg prefetch registers (gate threads only: tid < 32, coalesced)
        float xq0 = 0.f, xq1 = 0.f, xq2 = 0.f, xq3 = 0.f;
        if (tid < 32) {
            wait_chunk(dir ? 63 : 0);
            const float* xgt = xg + (size_t)(dir ? (L - 1) : 0) * G4;
            xq0 = aload_f(xgt + uu);            xq1 = aload_f(xgt + HH + uu);
            xq2 = aload_f(xgt + 2 * HH + uu);   xq3 = aload_f(xgt + 3 * HH + uu);
        }

        for (int s = 0; s < L; s++) {
            const int t = dir ? (L - 1 - s) : s;
            const int p = s & 1;

            // poll my single word of h[t-1], deposit into LDS
            unsigned int v = 0;              // s==0: h = 0
            if (s > 0) {
                const int tp = dir ? (t + 1) : (t - 1);
                const unsigned int* hp =
                    (const unsigned int*)(hout + (size_t)tp * HH) + tid;
                do {
                    v = __hip_atomic_load(hp, __ATOMIC_RELAXED,
                                          __HIP_MEMORY_SCOPE_AGENT);
                } while (v == SENT);
            }
            h_lds[p][tid] = __uint_as_float(v);
            __syncthreads();                               // barrier 1

            // matvec on my 8 strided cols for my wave's 16 rows
            float hv[8];
#pragma unroll
            for (int k = 0; k < 8; k++) hv[k] = h_lds[p][k * 64 + lane];

            float acc[16];
#pragma unroll
            for (int rr = 0; rr < 16; rr++) {
                float a = 0.f;
#pragma unroll
                for (int k = 0; k < 8; k++) a += w[rr][k] * hv[k];
                acc[rr] = a;
            }

            // register-compacting butterfly reduction across 64 lanes
            {
                const bool b0 = lane & 1;
#pragma unroll
                for (int r = 0; r < 8; r++) {
                    const float send = b0 ? acc[r] : acc[r + 8];
                    const float recv = __shfl_xor(send, 1, 64);
                    acc[r] = (b0 ? acc[r + 8] : acc[r]) + recv;
                }
                const bool b1 = lane & 2;
#pragma unroll
                for (int r = 0; r < 4; r++) {
                    const float send = b1 ? acc[r] : acc[r + 4];
                    const float recv = __shfl_xor(send, 2, 64);
                    acc[r] = (b1 ? acc[r + 4] : acc[r]) + recv;
                }
                const bool b2 = lane & 4;
#pragma unroll
                for (int r = 0; r < 2; r++) {
                    const float send = b2 ? acc[r] : acc[r + 2];
                    const float recv = __shfl_xor(send, 4, 64);
                    acc[r] = (b2 ? acc[r + 2] : acc[r]) + recv;
                }
                const bool b3 = lane & 8;
                {
                    const float send = b3 ? acc[0] : acc[1];
                    const float recv = __shfl_xor(send, 8, 64);
                    acc[0] = (b3 ? acc[1] : acc[0]) + recv;
                }
                acc[0] += __shfl_xor(acc[0], 16, 64);
                acc[0] += __shfl_xor(acc[0], 32, 64);
            }
            if (lane < 16) {
                const int R = ((lane & 1) << 3) | ((lane & 2) << 1) |
                              ((lane & 4) >> 1) | ((lane & 8) >> 3);
                glds[wave][R] = acc[0];
            }
            __syncthreads();                               // barrier 2

            // gate math + coalesced h store (32 gate threads = wave 0)
            if (tid < 32) {
                const int jh_ = tid >> 4;
                const int rr  = tid & 15;
                float iv = glds[0 + jh_][rr] + xq0;
                float fv = glds[2 + jh_][rr] + xq1;
                float gv = glds[4 + jh_][rr] + xq2;
                float ov = glds[6 + jh_][rr] + xq3;
                iv = 1.f / (1.f + expf(-iv));
                fv = 1.f / (1.f + expf(-fv));
                gv = tanhf(gv);
                ov = 1.f / (1.f + expf(-ov));
                c_state = fv * c_state + iv * gv;
                const float hval = ov * tanhf(c_state);
                __hip_atomic_store((unsigned int*)&hout[(size_t)t * HH + uu],
                                   __float_as_uint(hval), __ATOMIC_RELAXED,
                                   __HIP_MEMORY_SCOPE_AGENT);
                // prefetch next step's xg (off critical path; chunk-gated)
                if (s + 1 < L) {
                    const int tn = dir ? (t - 1) : (t + 1);
                    if ((tn & 63) == (dir ? 63 : 0)) wait_chunk(tn >> 6);
                    const float* xgt = xg + (size_t)tn * G4;
                    xq0 = aload_f(xgt + uu);
                    xq1 = aload_f(xgt + HH + uu);
                    xq2 = aload_f(xgt + 2 * HH + uu);
                    xq3 = aload_f(xgt + 3 * HH + uu);
                }
            }
            // no trailing barrier: ping-pong h_lds; glds rewritten only
            // after next barrier 1.
        }
        return;
    }

    // ====================== HELPER blocks ======================
    const int hid_ = bid - NWRK;         // 0..223

    // ---- Phase 1: xg tiles, timestep-ordered across both directions ----
    for (int tile = hid_; tile < NTILE; tile += NHELP) {
        const int jt = tile & 31;        // j-tile 0..31
        const int sd = tile >> 5;        // 0..127 = schunk*2 + dir
        const int dr = sd & 1;
        const int sc = sd >> 1;          // 0..63 (s-chunk, consumption order)
        const int t0 = dr ? (L - 64 - sc * 64) : (sc * 64);
        const int j0 = jt * 64;
        const float* __restrict__ wih = dr ? wih_b : wih_f;
        const float* __restrict__ bih = dr ? bih_b : bih_f;
        const float* __restrict__ bhh = dr ? bhh_b : bhh_f;
        float* __restrict__ xg = dr ? xg_b : xg_f;

        if (tid < 64) sent_s[tid] = sentence[t0 + tid];

        const int li = tid >> 3;         // 0..63
        const int k4 = (tid & 7) * 4;    // 0..28
        const int tx = tid & 15;         // col group (4 cols)
        const int ty = tid >> 4;         // row group (2 rows), 0..31

        float a00 = 0.f, a01 = 0.f, a02 = 0.f, a03 = 0.f;
        float a10 = 0.f, a11 = 0.f, a12 = 0.f, a13 = 0.f;

        for (int k0 = 0; k0 < E; k0 += 32) {
            __syncthreads();
            {
                const float4 av = *(const float4*)(emb + (size_t)sent_s[li] * E + k0 + k4);
                As[k4 + 0][li] = av.x; As[k4 + 1][li] = av.y;
                As[k4 + 2][li] = av.z; As[k4 + 3][li] = av.w;
                const float4 bv = *(const float4*)(wih + (size_t)(j0 + li) * E + k0 + k4);
                Bs[k4 + 0][li] = bv.x; Bs[k4 + 1][li] = bv.y;
                Bs[k4 + 2][li] = bv.z; Bs[k4 + 3][li] = bv.w;
            }
            __syncthreads();
#pragma unroll
            for (int k = 0; k < 32; k++) {
                const float a0 = As[k][ty * 2 + 0];
                const float a1 = As[k][ty * 2 + 1];
                const float4 b4 = *(const float4*)&Bs[k][tx * 4];
                a00 += a0 * b4.x; a01 += a0 * b4.y; a02 += a0 * b4.z; a03 += a0 * b4.w;
                a10 += a1 * b4.x; a11 += a1 * b4.y; a12 += a1 * b4.z; a13 += a1 * b4.w;
            }
        }

        // write-through (agent atomic) stores so cross-XCD readers see them
        {
            const int c0 = j0 + tx * 4;
            const float bsum0 = bih[c0 + 0] + bhh[c0 + 0];
            const float bsum1 = bih[c0 + 1] + bhh[c0 + 1];
            const float bsum2 = bih[c0 + 2] + bhh[c0 + 2];
            const float bsum3 = bih[c0 + 3] + bhh[c0 + 3];
            float* r0 = xg + (size_t)(t0 + ty * 2 + 0) * G4 + c0;
            float* r1 = xg + (size_t)(t0 + ty * 2 + 1) * G4 + c0;
            astore_f(r0 + 0, a00 + bsum0); astore_f(r0 + 1, a01 + bsum1);
            astore_f(r0 + 2, a02 + bsum2); astore_f(r0 + 3, a03 + bsum3);
            astore_f(r1 + 0, a10 + bsum0); astore_f(r1 + 1, a11 + bsum1);
            astore_f(r1 + 2, a12 + bsum2); astore_f(r1 + 3, a13 + bsum3);
        }
        __syncthreads();   // drain all threads' stores (vmcnt) before publish
        if (tid == 0)
            __hip_atomic_fetch_add(&cnt[dr * 64 + (t0 >> 6)], 1,
                                   __ATOMIC_RELEASE, __HIP_MEMORY_SCOPE_AGENT);
    }

    // ---- Phase 2: feats rows, polling h sentinels ----
    const int wave = tid >> 6, lane = tid & 63;
    for (int t = hid_; t < L; t += NHELP) {
        // cheap pre-gate: one indicator word per producer block, with backoff
        if (tid < 32) {
            const float* src = (tid < 16) ? hf : hb;
            const unsigned int* wp =
                (const unsigned int*)(src + (size_t)t * HH) + (tid & 15) * 32;
            while (__hip_atomic_load(wp, __ATOMIC_RELAXED,
                                     __HIP_MEMORY_SCOPE_AGENT) == SENT) {
                __builtin_amdgcn_s_sleep(8);
            }
        }
        __syncthreads();

        // full read (per-word sentinel verify; stragglers re-polled tightly)
        const unsigned int* p0 = (const unsigned int*)(hf + (size_t)t * HH) + tid;
        const unsigned int* p1 = (const unsigned int*)(hb + (size_t)t * HH) + tid;
        unsigned int v0, v1;
        do { v0 = __hip_atomic_load(p0, __ATOMIC_RELAXED,
                                    __HIP_MEMORY_SCOPE_AGENT); } while (v0 == SENT);
        do { v1 = __hip_atomic_load(p1, __ATOMIC_RELAXED,
                                    __HIP_MEMORY_SCOPE_AGENT); } while (v1 == SENT);
        const float x0 = __uint_as_float(v0);
        const float x1 = __uint_as_float(v1);

        float acc[T_TAG];
#pragma unroll
        for (int i = 0; i < T_TAG; i++)
            acc[i] = x0 * wout[i * HID + tid] + x1 * wout[i * HID + HH + tid];
#pragma unroll
        for (int m = 1; m < 64; m <<= 1) {
#pragma unroll
            for (int i = 0; i < T_TAG; i++) acc[i] += __shfl_xor(acc[i], m, 64);
        }
        if (lane == 0) {
#pragma unroll
            for (int i = 0; i < T_TAG; i++) red_s[wave][i] = acc[i];
        }
        __syncthreads();
        if (tid < T_TAG) {
            float ssum = bout[tid];
#pragma unroll
            for (int wv = 0; wv < 8; wv++) ssum += red_s[wv][tid];
            feats[(size_t)t * 8 + tid] = ssum;
        }
        __syncthreads();   // protect red_s reuse
    }
}

// ---------------------------------------------------------------------------
// Viterbi forward + backtrace.  One wave.
// ---------------------------------------------------------------------------
__global__ __launch_bounds__(64)
void viterbi_kernel(const float* __restrict__ feats, const float* __restrict__ trans,
                    float* __restrict__ out)
{
    __shared__ unsigned char bp[L][T_TAG];

    const int tid = threadIdx.x;     // 0..63
    const int i = tid >> 3, j = tid & 7;
    const bool valid = (i < T_TAG) && (j < T_TAG);
    const float trij = valid ? trans[i * T_TAG + j] : -1e30f;

    float fv;
    if (j < T_TAG) fv = (j == START_TAG) ? 0.f : NEGV;
    else           fv = -1e30f;

    const int ieff = (i < T_TAG) ? i : 0;
    float fq[8];
#pragma unroll
    for (int p = 0; p < 8; p++) fq[p] = feats[(size_t)p * 8 + ieff];

    for (int t = 0; t < L; t++) {
        const float sc = fv + trij;
        float best = sc; int bj = j;
#pragma unroll
        for (int m = 1; m < 8; m <<= 1) {
            const float ov = __shfl_xor(best, m, 8);
            const int   oj = __shfl_xor(bj, m, 8);
            if (ov > best || (ov == best && oj < bj)) { best = ov; bj = oj; }
        }
        const float f_t = fq[t & 7];
        if (t + 8 < L) fq[t & 7] = feats[(size_t)(t + 8) * 8 + ieff];
        const float fvnew = best + f_t;          // for dest tag == i
        if (valid && j == 0) bp[t][i] = (unsigned char)bj;
        const float nf = __shfl(fvnew, (j < T_TAG) ? j * 8 : 0, 64);
        fv = (j < T_TAG) ? nf : -1e30f;
    }

    float term = fv + ((j < T_TAG) ? trans[STOP_TAG * T_TAG + j] : -1e30f);
    float bestt = term; int bt = j;
#pragma unroll
    for (int m = 1; m < 8; m <<= 1) {
        const float ov = __shfl_xor(bestt, m, 8);
        const int   oj = __shfl_xor(bt, m, 8);
        if (ov > bestt || (ov == bestt && oj < bt)) { bestt = ov; bt = oj; }
    }

    if (tid == 0) {
        out[L] = bestt;
        int tag = bt;
        out[L - 1] = (float)tag;
        for (int t = L - 1; t >= 1; t--) {
            tag = bp[t][tag];
            out[t - 1] = (float)tag;
        }
    }
}

// ---------------------------------------------------------------------------
extern "C" void kernel_launch(void* const* d_in, const int* in_sizes, int n_in,
                              void* d_out, int out_size, void* d_ws, size_t ws_size,
                              hipStream_t stream)
{
    const int*   sentence = (const int*)  d_in[0];
    const float* emb      = (const float*)d_in[1];
    const float* wih_f    = (const float*)d_in[2];
    const float* whh_f    = (const float*)d_in[3];
    const float* bih_f    = (const float*)d_in[4];
    const float* bhh_f    = (const float*)d_in[5];
    const float* wih_b    = (const float*)d_in[6];
    const float* whh_b    = (const float*)d_in[7];
    const float* bih_b    = (const float*)d_in[8];
    const float* bhh_b    = (const float*)d_in[9];
    const float* wout     = (const float*)d_in[10];
    const float* bout     = (const float*)d_in[11];
    const float* trans    = (const float*)d_in[12];
    float* out = (float*)d_out;

    char* ws = (char*)d_ws;
    int*   cnt    = (int*)ws;                                   // 1 KiB
    float* xg_f   = (float*)(ws + 1024);
    float* xg_b   = xg_f  + (size_t)L * G4;
    float* hfbuf  = xg_b  + (size_t)L * G4;
    float* hbbuf  = hfbuf + (size_t)L * HH;
    float* featsb = hbbuf + (size_t)L * HH;
    // total: 1024 + 2*L*G4*4 + 2*L*HH*4 + L*8*4  ~= 84 MB

    // readiness counters -> 0; h buffers -> sentinel (0xFF bytes = -NaN)
    hipMemsetAsync(cnt, 0, 1024, stream);
    hipMemsetAsync(hfbuf, 0xFF, (size_t)2 * L * HH * sizeof(float), stream);

    void* args[] = { (void*)&sentence, (void*)&emb,
                     (void*)&wih_f, (void*)&bih_f, (void*)&bhh_f,
                     (void*)&wih_b, (void*)&bih_b, (void*)&bhh_b,
                     (void*)&whh_f, (void*)&whh_b,
                     (void*)&wout, (void*)&bout,
                     (void*)&xg_f, (void*)&xg_b,
                     (void*)&hfbuf, (void*)&hbbuf,
                     (void*)&featsb, (void*)&cnt };
    hipLaunchCooperativeKernel((void*)fused_kernel, dim3(NWRK + NHELP),
                               dim3(512), args, 0, stream);

    hipLaunchKernelGGL(viterbi_kernel, dim3(1), dim3(64), 0, stream,
                       featsb, trans, out);
}

// Round 10
// 9090.573 us; speedup vs baseline: 1.3557x; 1.0789x over previous
//
#include <hip/hip_runtime.h>
#include <hip/hip_bf16.h>

// Problem constants (fixed by the reference)
#define L     4096
#define E     512
#define HID   1024
#define HH    512          // H per direction
#define G4    2048         // 4*H gate rows
#define T_TAG 7
#define START_TAG 4
#define STOP_TAG  5
#define NEGV  (-10000.0f)

#define NWRK  32           // worker blocks (16 per direction)
#define NHELP 224          // helper blocks (xg tiles, then feats rows)
#define NTILE (64 * 2 * 32)  // (L/64 s-chunks) x 2 dirs x (G4/64 j-tiles)
#define SENT  0xFFFFFFFFu  // h sentinel: -NaN, unreachable for real h values

__device__ __forceinline__ float aload_f(const float* p) {
    const unsigned int v = __hip_atomic_load((const unsigned int*)p,
                                             __ATOMIC_RELAXED,
                                             __HIP_MEMORY_SCOPE_AGENT);
    return __uint_as_float(v);
}
__device__ __forceinline__ void astore_f(float* p, float x) {
    __hip_atomic_store((unsigned int*)p, __float_as_uint(x),
                       __ATOMIC_RELAXED, __HIP_MEMORY_SCOPE_AGENT);
}

// ---------------------------------------------------------------------------
// Fused cooperative kernel, 256 blocks x 512.  (unchanged from R9 — measured
// at the recurrence floor 7.8ms with helpers fully hidden)
//  blocks 0..31   : bidirectional LSTM recurrence
//  blocks 32..255 : helpers. Phase 1: xg tiles (timestep order, readiness
//                   counters).  Phase 2: feats rows (poll h sentinels).
// ---------------------------------------------------------------------------
__global__ __launch_bounds__(512)
void fused_kernel(const int* __restrict__ sentence, const float* __restrict__ emb,
                  const float* __restrict__ wih_f, const float* __restrict__ bih_f,
                  const float* __restrict__ bhh_f,
                  const float* __restrict__ wih_b, const float* __restrict__ bih_b,
                  const float* __restrict__ bhh_b,
                  const float* __restrict__ whh_f, const float* __restrict__ whh_b,
                  const float* __restrict__ wout, const float* __restrict__ bout,
                  float* __restrict__ xg_f, float* __restrict__ xg_b,
                  float* __restrict__ hf, float* __restrict__ hb,
                  float* __restrict__ feats, int* cnt)
{
    const int bid = blockIdx.x;
    const int tid = threadIdx.x;

    __shared__ float h_lds[2][HH];    // worker: ping-pong h staging
    __shared__ float glds[8][16];     // worker: per-wave row sums
    __shared__ float As[32][68];      // helper: x tile
    __shared__ float Bs[32][68];      // helper: w_ih tile
    __shared__ int   sent_s[64];      // helper: sentence ids
    __shared__ float red_s[8][8];     // helper: feats reduction

    if (bid < NWRK) {
        // =================== WORKER: LSTM recurrence ===================
        const int dir = bid >> 4;            // 0 fwd, 1 bwd
        const int rnk = bid & 15;            // 0..15

        const float* __restrict__ xg  = dir ? xg_b  : xg_f;
        const float* __restrict__ whh = dir ? whh_b : whh_f;
        float* __restrict__ hout = dir ? hb : hf;

        const int wave = tid >> 6;
        const int lane = tid & 63;
        const int g    = wave >> 1;          // gate: 0=i 1=f 2=g 3=o
        const int jh   = wave & 1;           // unit half
        const int u0   = rnk * 32;

        float w[16][8];
#pragma unroll
        for (int rr = 0; rr < 16; rr++) {
            const size_t row = (size_t)(g * HH + u0 + jh * 16 + rr);
#pragma unroll
            for (int k = 0; k < 8; k++)
                w[rr][k] = whh[row * HH + (size_t)(k * 64 + lane)];
        }

        float c_state = 0.f;                 // live only for tid < 32
        const int uu = u0 + (tid & 31);

        auto wait_chunk = [&](int tc) {
            const int* cp = cnt + dir * 64 + tc;
            while (__hip_atomic_load(cp, __ATOMIC_ACQUIRE,
                                     __HIP_MEMORY_SCOPE_AGENT) < 32) {
                __builtin_amdgcn_s_sleep(1);
            }
        };

        float xq0 = 0.f, xq1 = 0.f, xq2 = 0.f, xq3 = 0.f;
        if (tid < 32) {
            wait_chunk(dir ? 63 : 0);
            const float* xgt = xg + (size_t)(dir ? (L - 1) : 0) * G4;
            xq0 = aload_f(xgt + uu);            xq1 = aload_f(xgt + HH + uu);
            xq2 = aload_f(xgt + 2 * HH + uu);   xq3 = aload_f(xgt + 3 * HH + uu);
        }

        for (int s = 0; s < L; s++) {
            const int t = dir ? (L - 1 - s) : s;
            const int p = s & 1;

            unsigned int v = 0;              // s==0: h = 0
            if (s > 0) {
                const int tp = dir ? (t + 1) : (t - 1);
                const unsigned int* hp =
                    (const unsigned int*)(hout + (size_t)tp * HH) + tid;
                do {
                    v = __hip_atomic_load(hp, __ATOMIC_RELAXED,
                                          __HIP_MEMORY_SCOPE_AGENT);
                } while (v == SENT);
            }
            h_lds[p][tid] = __uint_as_float(v);
            __syncthreads();                               // barrier 1

            float hv[8];
#pragma unroll
            for (int k = 0; k < 8; k++) hv[k] = h_lds[p][k * 64 + lane];

            float acc[16];
#pragma unroll
            for (int rr = 0; rr < 16; rr++) {
                float a = 0.f;
#pragma unroll
                for (int k = 0; k < 8; k++) a += w[rr][k] * hv[k];
                acc[rr] = a;
            }

            {
                const bool b0 = lane & 1;
#pragma unroll
                for (int r = 0; r < 8; r++) {
                    const float send = b0 ? acc[r] : acc[r + 8];
                    const float recv = __shfl_xor(send, 1, 64);
                    acc[r] = (b0 ? acc[r + 8] : acc[r]) + recv;
                }
                const bool b1 = lane & 2;
#pragma unroll
                for (int r = 0; r < 4; r++) {
                    const float send = b1 ? acc[r] : acc[r + 4];
                    const float recv = __shfl_xor(send, 2, 64);
                    acc[r] = (b1 ? acc[r + 4] : acc[r]) + recv;
                }
                const bool b2 = lane & 4;
#pragma unroll
                for (int r = 0; r < 2; r++) {
                    const float send = b2 ? acc[r] : acc[r + 2];
                    const float recv = __shfl_xor(send, 4, 64);
                    acc[r] = (b2 ? acc[r + 2] : acc[r]) + recv;
                }
                const bool b3 = lane & 8;
                {
                    const float send = b3 ? acc[0] : acc[1];
                    const float recv = __shfl_xor(send, 8, 64);
                    acc[0] = (b3 ? acc[1] : acc[0]) + recv;
                }
                acc[0] += __shfl_xor(acc[0], 16, 64);
                acc[0] += __shfl_xor(acc[0], 32, 64);
            }
            if (lane < 16) {
                const int R = ((lane & 1) << 3) | ((lane & 2) << 1) |
                              ((lane & 4) >> 1) | ((lane & 8) >> 3);
                glds[wave][R] = acc[0];
            }
            __syncthreads();                               // barrier 2

            if (tid < 32) {
                const int jh_ = tid >> 4;
                const int rr  = tid & 15;
                float iv = glds[0 + jh_][rr] + xq0;
                float fv = glds[2 + jh_][rr] + xq1;
                float gv = glds[4 + jh_][rr] + xq2;
                float ov = glds[6 + jh_][rr] + xq3;
                iv = 1.f / (1.f + expf(-iv));
                fv = 1.f / (1.f + expf(-fv));
                gv = tanhf(gv);
                ov = 1.f / (1.f + expf(-ov));
                c_state = fv * c_state + iv * gv;
                const float hval = ov * tanhf(c_state);
                __hip_atomic_store((unsigned int*)&hout[(size_t)t * HH + uu],
                                   __float_as_uint(hval), __ATOMIC_RELAXED,
                                   __HIP_MEMORY_SCOPE_AGENT);
                if (s + 1 < L) {
                    const int tn = dir ? (t - 1) : (t + 1);
                    if ((tn & 63) == (dir ? 63 : 0)) wait_chunk(tn >> 6);
                    const float* xgt = xg + (size_t)tn * G4;
                    xq0 = aload_f(xgt + uu);
                    xq1 = aload_f(xgt + HH + uu);
                    xq2 = aload_f(xgt + 2 * HH + uu);
                    xq3 = aload_f(xgt + 3 * HH + uu);
                }
            }
        }
        return;
    }

    // ====================== HELPER blocks ======================
    const int hid_ = bid - NWRK;         // 0..223

    // ---- Phase 1: xg tiles, timestep-ordered across both directions ----
    for (int tile = hid_; tile < NTILE; tile += NHELP) {
        const int jt = tile & 31;
        const int sd = tile >> 5;
        const int dr = sd & 1;
        const int sc = sd >> 1;
        const int t0 = dr ? (L - 64 - sc * 64) : (sc * 64);
        const int j0 = jt * 64;
        const float* __restrict__ wih = dr ? wih_b : wih_f;
        const float* __restrict__ bih = dr ? bih_b : bih_f;
        const float* __restrict__ bhh = dr ? bhh_b : bhh_f;
        float* __restrict__ xg = dr ? xg_b : xg_f;

        if (tid < 64) sent_s[tid] = sentence[t0 + tid];

        const int li = tid >> 3;
        const int k4 = (tid & 7) * 4;
        const int tx = tid & 15;
        const int ty = tid >> 4;

        float a00 = 0.f, a01 = 0.f, a02 = 0.f, a03 = 0.f;
        float a10 = 0.f, a11 = 0.f, a12 = 0.f, a13 = 0.f;

        for (int k0 = 0; k0 < E; k0 += 32) {
            __syncthreads();
            {
                const float4 av = *(const float4*)(emb + (size_t)sent_s[li] * E + k0 + k4);
                As[k4 + 0][li] = av.x; As[k4 + 1][li] = av.y;
                As[k4 + 2][li] = av.z; As[k4 + 3][li] = av.w;
                const float4 bv = *(const float4*)(wih + (size_t)(j0 + li) * E + k0 + k4);
                Bs[k4 + 0][li] = bv.x; Bs[k4 + 1][li] = bv.y;
                Bs[k4 + 2][li] = bv.z; Bs[k4 + 3][li] = bv.w;
            }
            __syncthreads();
#pragma unroll
            for (int k = 0; k < 32; k++) {
                const float a0 = As[k][ty * 2 + 0];
                const float a1 = As[k][ty * 2 + 1];
                const float4 b4 = *(const float4*)&Bs[k][tx * 4];
                a00 += a0 * b4.x; a01 += a0 * b4.y; a02 += a0 * b4.z; a03 += a0 * b4.w;
                a10 += a1 * b4.x; a11 += a1 * b4.y; a12 += a1 * b4.z; a13 += a1 * b4.w;
            }
        }

        {
            const int c0 = j0 + tx * 4;
            const float bsum0 = bih[c0 + 0] + bhh[c0 + 0];
            const float bsum1 = bih[c0 + 1] + bhh[c0 + 1];
            const float bsum2 = bih[c0 + 2] + bhh[c0 + 2];
            const float bsum3 = bih[c0 + 3] + bhh[c0 + 3];
            float* r0 = xg + (size_t)(t0 + ty * 2 + 0) * G4 + c0;
            float* r1 = xg + (size_t)(t0 + ty * 2 + 1) * G4 + c0;
            astore_f(r0 + 0, a00 + bsum0); astore_f(r0 + 1, a01 + bsum1);
            astore_f(r0 + 2, a02 + bsum2); astore_f(r0 + 3, a03 + bsum3);
            astore_f(r1 + 0, a10 + bsum0); astore_f(r1 + 1, a11 + bsum1);
            astore_f(r1 + 2, a12 + bsum2); astore_f(r1 + 3, a13 + bsum3);
        }
        __syncthreads();
        if (tid == 0)
            __hip_atomic_fetch_add(&cnt[dr * 64 + (t0 >> 6)], 1,
                                   __ATOMIC_RELEASE, __HIP_MEMORY_SCOPE_AGENT);
    }

    // ---- Phase 2: feats rows, polling h sentinels ----
    const int wave = tid >> 6, lane = tid & 63;
    for (int t = hid_; t < L; t += NHELP) {
        if (tid < 32) {
            const float* src = (tid < 16) ? hf : hb;
            const unsigned int* wp =
                (const unsigned int*)(src + (size_t)t * HH) + (tid & 15) * 32;
            while (__hip_atomic_load(wp, __ATOMIC_RELAXED,
                                     __HIP_MEMORY_SCOPE_AGENT) == SENT) {
                __builtin_amdgcn_s_sleep(8);
            }
        }
        __syncthreads();

        const unsigned int* p0 = (const unsigned int*)(hf + (size_t)t * HH) + tid;
        const unsigned int* p1 = (const unsigned int*)(hb + (size_t)t * HH) + tid;
        unsigned int v0, v1;
        do { v0 = __hip_atomic_load(p0, __ATOMIC_RELAXED,
                                    __HIP_MEMORY_SCOPE_AGENT); } while (v0 == SENT);
        do { v1 = __hip_atomic_load(p1, __ATOMIC_RELAXED,
                                    __HIP_MEMORY_SCOPE_AGENT); } while (v1 == SENT);
        const float x0 = __uint_as_float(v0);
        const float x1 = __uint_as_float(v1);

        float acc[T_TAG];
#pragma unroll
        for (int i = 0; i < T_TAG; i++)
            acc[i] = x0 * wout[i * HID + tid] + x1 * wout[i * HID + HH + tid];
#pragma unroll
        for (int m = 1; m < 64; m <<= 1) {
#pragma unroll
            for (int i = 0; i < T_TAG; i++) acc[i] += __shfl_xor(acc[i], m, 64);
        }
        if (lane == 0) {
#pragma unroll
            for (int i = 0; i < T_TAG; i++) red_s[wave][i] = acc[i];
        }
        __syncthreads();
        if (tid < T_TAG) {
            float ssum = bout[tid];
#pragma unroll
            for (int wv = 0; wv < 8; wv++) ssum += red_s[wv][tid];
            feats[(size_t)t * 8 + tid] = ssum;
        }
        __syncthreads();
    }
}

// ---------------------------------------------------------------------------
// Viterbi forward + backtrace.  One wave.
// FIX (rule #20): the feats register queue is now STATIC-indexed via an
// 8x unrolled loop (fq[q], q compile-time) -> stays in VGPRs, no scratch.
// Main loop branch-free prefetch; tail block (last 8 steps) without.
// ---------------------------------------------------------------------------
__global__ __launch_bounds__(64)
void viterbi_kernel(const float* __restrict__ feats, const float* __restrict__ trans,
                    float* __restrict__ out)
{
    __shared__ unsigned char bp[L][T_TAG];

    const int tid = threadIdx.x;     // 0..63
    const int i = tid >> 3, j = tid & 7;
    const bool valid = (i < T_TAG) && (j < T_TAG);
    const float trij = valid ? trans[i * T_TAG + j] : -1e30f;

    float fv;
    if (j < T_TAG) fv = (j == START_TAG) ? 0.f : NEGV;
    else           fv = -1e30f;

    const int ieff = (i < T_TAG) ? i : 0;
    float fq[8];
#pragma unroll
    for (int q = 0; q < 8; q++) fq[q] = feats[(size_t)q * 8 + ieff];

#define VSTEP(T, Q, PREFETCH)                                                  \
    {                                                                          \
        const float sc = fv + trij;                                            \
        float best = sc; int bj = j;                                           \
        _Pragma("unroll")                                                      \
        for (int m = 1; m < 8; m <<= 1) {                                      \
            const float ov = __shfl_xor(best, m, 8);                           \
            const int   oj = __shfl_xor(bj, m, 8);                             \
            if (ov > best || (ov == best && oj < bj)) { best = ov; bj = oj; }  \
        }                                                                      \
        const float f_t = fq[Q];                                               \
        if (PREFETCH) fq[Q] = feats[(size_t)((T) + 8) * 8 + ieff];             \
        const float fvnew = best + f_t;                                        \
        if (valid && j == 0) bp[(T)][i] = (unsigned char)bj;                   \
        const float nf = __shfl(fvnew, (j < T_TAG) ? j * 8 : 0, 64);           \
        fv = (j < T_TAG) ? nf : -1e30f;                                        \
    }

    for (int tb = 0; tb < L - 8; tb += 8) {
#pragma unroll
        for (int q = 0; q < 8; q++) VSTEP(tb + q, q, true)
    }
    {
        const int tb = L - 8;
#pragma unroll
        for (int q = 0; q < 8; q++) VSTEP(tb + q, q, false)
    }
#undef VSTEP

    float term = fv + ((j < T_TAG) ? trans[STOP_TAG * T_TAG + j] : -1e30f);
    float bestt = term; int bt = j;
#pragma unroll
    for (int m = 1; m < 8; m <<= 1) {
        const float ov = __shfl_xor(bestt, m, 8);
        const int   oj = __shfl_xor(bt, m, 8);
        if (ov > bestt || (ov == bestt && oj < bt)) { bestt = ov; bt = oj; }
    }

    if (tid == 0) {
        out[L] = bestt;
        int tag = bt;
        out[L - 1] = (float)tag;
        for (int t = L - 1; t >= 1; t--) {
            tag = bp[t][tag];
            out[t - 1] = (float)tag;
        }
    }
}

// ---------------------------------------------------------------------------
extern "C" void kernel_launch(void* const* d_in, const int* in_sizes, int n_in,
                              void* d_out, int out_size, void* d_ws, size_t ws_size,
                              hipStream_t stream)
{
    const int*   sentence = (const int*)  d_in[0];
    const float* emb      = (const float*)d_in[1];
    const float* wih_f    = (const float*)d_in[2];
    const float* whh_f    = (const float*)d_in[3];
    const float* bih_f    = (const float*)d_in[4];
    const float* bhh_f    = (const float*)d_in[5];
    const float* wih_b    = (const float*)d_in[6];
    const float* whh_b    = (const float*)d_in[7];
    const float* bih_b    = (const float*)d_in[8];
    const float* bhh_b    = (const float*)d_in[9];
    const float* wout     = (const float*)d_in[10];
    const float* bout     = (const float*)d_in[11];
    const float* trans    = (const float*)d_in[12];
    float* out = (float*)d_out;

    char* ws = (char*)d_ws;
    int*   cnt    = (int*)ws;                                   // 1 KiB
    float* xg_f   = (float*)(ws + 1024);
    float* xg_b   = xg_f  + (size_t)L * G4;
    float* hfbuf  = xg_b  + (size_t)L * G4;
    float* hbbuf  = hfbuf + (size_t)L * HH;
    float* featsb = hbbuf + (size_t)L * HH;
    // total: 1024 + 2*L*G4*4 + 2*L*HH*4 + L*8*4  ~= 84 MB

    hipMemsetAsync(cnt, 0, 1024, stream);
    hipMemsetAsync(hfbuf, 0xFF, (size_t)2 * L * HH * sizeof(float), stream);

    void* args[] = { (void*)&sentence, (void*)&emb,
                     (void*)&wih_f, (void*)&bih_f, (void*)&bhh_f,
                     (void*)&wih_b, (void*)&bih_b, (void*)&bhh_b,
                     (void*)&whh_f, (void*)&whh_b,
                     (void*)&wout, (void*)&bout,
                     (void*)&xg_f, (void*)&xg_b,
                     (void*)&hfbuf, (void*)&hbbuf,
                     (void*)&featsb, (void*)&cnt };
    hipLaunchCooperativeKernel((void*)fused_kernel, dim3(NWRK + NHELP),
                               dim3(512), args, 0, stream);

    hipLaunchKernelGGL(viterbi_kernel, dim3(1), dim3(64), 0, stream,
                       featsb, trans, out);
}